// Round 8
// baseline (264.498 us; speedup 1.0000x reference)
//
#include <hip/hip_runtime.h>

// RelatEntAtt: E=4096, R=64, D=256. Fully fused recompute; att (E,R,D) never
// materialized. exp2 with log2(e) folded into the adj-softmax output.
// R2 (180.9us): CH=8, JT=16, arrays SROA to regs. Grid 512 -> 18% occ.
// R3/R4 (FAILED): CH=4 breaks SROA (~470 MB scratch). CH=8 + JT=16 private
//     array shapes are load-bearing. DO NOT TOUCH.
// R5 (181us): j-half split, grid 1024. SROA held -> orchestration edits safe.
// R6 (170us, PASSED): j-quarter split, grid 2048. kB 58.5us @ VALUBusy 66%.
// R7 (FAILED): hipLaunchCooperativeKernel incompatible with harness.
// R8 (FAILED): spin grid-barrier -> no output (likely deadlock). NO SPINS.
// R9 (FAILED, absmax 58): last-arriver tails read PARTIALLY-accumulated racc:
//     agent acquire fence does not give in-kernel plain-load visibility of
//     remote-XCD atomics. LESSON: atomic results may only be consumed across
//     a kernel boundary. No intra-kernel cross-block consumption.
// R10: back to R6 structure (4 stream ops, kernel-boundary sync only).
//     (a) kB alog reduction: scan-style row16_sum (4 serial DPP-adds PER
//         element, ~64 DPP-adds/ee) -> bisection multi-reduce (15 exchange+add
//         for all 16 jj at once), ~-20% kB VALU. Reduction order change only.
//     (b) k_adj folded into kA: kA computes adj-softmax in-block, writes its
//         s2 quarter to global; kB reads it across the kernel boundary
//         (consistency by construction). kA zeroes racc+sEg (not its own
//         buffers); memset covers lE+lRg.

#define EN 4096
#define RN 64
#define DN 256
#define JT 16          // j-tile width (PROVEN SROA shape - do not change)
#define LOG2E 1.44269504088896340736f
#define CHA 8   // e's per block (PROVEN SROA shape - do not change)
#define CHB 8
#define GRIDAB ((EN/CHA)*4)            // 2048 blocks: (e-chunk, j-quarter)
#define NZ4 ((RN*DN + EN*DN)/4)        // float4 count of racc+sEg (kA zeroes)

__device__ __forceinline__ float ex2(float x){ return __builtin_amdgcn_exp2f(x); }
__device__ __forceinline__ float rcpf(float x){ return __builtin_amdgcn_rcpf(x); }

// ---- kA: lRg[e,d] += sum_(own j) ev;  lE[j,d] += ev ----
// Computes adj-softmax for its 8 e-rows in-block (wave-per-row), keeps own
// j-quarter in LDS and publishes it to global s2 for kB. Zeroes racc+sEg.
__global__ __launch_bounds__(256,4) void kA(const float* __restrict__ h,
                                            const float* __restrict__ r,
                                            const float* __restrict__ adj,
                                            float* __restrict__ s2g,
                                            float* __restrict__ lRg,
                                            float* __restrict__ lE,
                                            float4* __restrict__ zb){ // racc+sEg
  const int d  = threadIdx.x;
  const int b  = blockIdx.x;
  const int e0 = (b >> 2) * CHA;
  const int j0 = (b & 3) * JT;

  // zero racc+sEg for kB (kA never touches them -> race-free; kernel boundary
  // publishes to kB)
  for(int i = b*256 + d; i < NZ4; i += GRIDAB*256)
    zb[i] = make_float4(0.f, 0.f, 0.f, 0.f);

  // adj softmax: wave w handles rows w and w+4; lane = j over full 64-j row
  __shared__ float s2s[CHA*JT];            // 512 B
  {
    const int w = d >> 6, lane = d & 63;
    #pragma unroll
    for(int rr2 = 0; rr2 < 2; rr2++){
      const int row = rr2*4 + w;
      float a  = adj[(e0 + row)*RN + lane];
      float ev = ex2(a * LOG2E);
      float s  = ev;
      #pragma unroll
      for(int off = 32; off > 0; off >>= 1) s += __shfl_xor(s, off, 64);
      float val = ev * (LOG2E * rcpf(s));
      const unsigned lj = (unsigned)(lane - j0);
      if(lj < 16u){
        s2s[row*JT + (int)lj] = val;              // own quarter for this block
        s2g[(e0 + row)*RN + j0 + (int)lj] = val;  // publish for kB (unique owner)
      }
    }
  }
  __syncthreads();

  float lR[CHA];
  #pragma unroll
  for(int ee = 0; ee < CHA; ee++) lR[ee] = 0.f;

  float rcol[JT], lEacc[JT];
  #pragma unroll
  for(int jj = 0; jj < JT; jj++){ rcol[jj] = r[(j0+jj)*DN + d]; lEacc[jj] = 0.f; }
  #pragma unroll
  for(int ee = 0; ee < CHA; ee++){
    const float he = h[(e0+ee)*DN + d];
    #pragma unroll
    for(int jj = 0; jj < JT; jj++){
      float t  = s2s[ee*JT + jj] * he * rcol[jj];
      float ev = ex2(fmaxf(t, 0.2f*t));
      lR[ee]   += ev;
      lEacc[jj] += ev;
    }
  }
  #pragma unroll
  for(int jj = 0; jj < JT; jj++) atomicAdd(&lE[(j0+jj)*DN + d], lEacc[jj]);
  #pragma unroll
  for(int ee = 0; ee < CHA; ee++) atomicAdd(&lRg[(e0+ee)*DN + d], lR[ee]);
}

// ---- kB: main fused sweep over own j-quarter ----
// per (e,d): pR = ev/lRg (att_R), pE = ev/lE (att_E)
//   sEg[e,d] += sum_(own j) pE      (atomics; h' ELU in kTail)
//   r'[j,d] += pR                   16-reg acc, atomic flush
//   alog[e,j] = sum_d pR*W_d        bisection multi-reduce + LDS group combine
__global__ __launch_bounds__(256,4) void kB(const float* __restrict__ h,
                                            const float* __restrict__ r,
                                            const float* __restrict__ s2,
                                            const float* __restrict__ lRg,
                                            const float* __restrict__ lE,
                                            const float* __restrict__ W,
                                            float* __restrict__ alog,
                                            float* __restrict__ racc_g,
                                            float* __restrict__ sEg){
  const int tid  = threadIdx.x;            // = d
  const int lane = tid & 63;
  const int grp  = tid >> 4;               // 16 groups of 16 lanes
  const int b    = blockIdx.x;
  const int e0   = (b >> 2) * CHB;
  const int j0   = (b & 3) * JT;
  __shared__ float s2s[CHB*JT];            // 512 B
  __shared__ float apart[CHB*16*20];       // [ee][g][jj], jj stride 1, g stride 20 -> 10 KB
  if(tid < CHB*JT) s2s[tid] = s2[(e0 + (tid >> 4))*RN + j0 + (tid & 15)];
  __syncthreads();

  const float wd = W[tid];
  float sE[CHB];
  #pragma unroll
  for(int ee = 0; ee < CHB; ee++) sE[ee] = 0.f;

  float rcol[JT], ile[JT], rAcc[JT];
  #pragma unroll
  for(int jj = 0; jj < JT; jj++){
    const int j = j0 + jj;
    rcol[jj] = r[j*DN + tid];
    ile[jj]  = rcpf(lE[j*DN + tid]);
    rAcc[jj] = 0.f;
  }
  const bool l8 = (lane & 8) != 0;
  const bool l4 = (lane & 4) != 0;
  const bool l2 = (lane & 2) != 0;
  const bool l1 = (lane & 1) != 0;
  for(int ee = 0; ee < CHB; ee++){
    const int e = e0 + ee;
    const float he = h[e*DN + tid];
    const float il = rcpf(lRg[e*DN + tid]);
    const float u  = il * wd;
    float aw[JT];
    #pragma unroll
    for(int jj = 0; jj < JT; jj++){
      float t  = s2s[ee*JT + jj] * he * rcol[jj];
      float ev = ex2(fmaxf(t, 0.2f*t));
      rAcc[jj] = fmaf(ev, il, rAcc[jj]);      // pR accumulated over e
      sE[ee]   = fmaf(ev, ile[jj], sE[ee]);   // pE sum over own j
      aw[jj]   = ev * u;                      // alog contribution
    }
    // bisection multi-reduce: 16 values over each 16-lane group in 15 steps.
    // After step for mask m, surviving slot i holds value-index i + (lane&sum
    // of processed masks); final: lane g*16+l holds sum over group of aw[l].
    float b8[8];
    #pragma unroll
    for(int i = 0; i < 8; i++){
      float send = l8 ? aw[i] : aw[i+8];
      float got  = __shfl_xor(send, 8, 64);
      b8[i] = (l8 ? aw[i+8] : aw[i]) + got;
    }
    float c4[4];
    #pragma unroll
    for(int i = 0; i < 4; i++){
      float send = l4 ? b8[i] : b8[i+4];
      float got  = __shfl_xor(send, 4, 64);
      c4[i] = (l4 ? b8[i+4] : b8[i]) + got;
    }
    float d2[2];
    #pragma unroll
    for(int i = 0; i < 2; i++){
      float send = l2 ? c4[i] : c4[i+2];
      float got  = __shfl_xor(send, 2, 64);
      d2[i] = (l2 ? c4[i+2] : c4[i]) + got;
    }
    {
      float send = l1 ? d2[0] : d2[1];
      float got  = __shfl_xor(send, 1, 64);
      float f0   = (l1 ? d2[1] : d2[0]) + got;
      apart[(ee*16 + grp)*20 + (lane & 15)] = f0;   // group-partial for jj=lane&15
    }
  }
  __syncthreads();
  if(tid < CHB*JT){                        // 128 threads: ee = tid>>4, jj = tid&15
    const int ee = tid >> 4, jj = tid & 15;
    float sum = 0.f;
    #pragma unroll
    for(int g = 0; g < 16; g++) sum += apart[(ee*16 + g)*20 + jj];
    alog[(e0+ee)*RN + j0 + jj] = sum;
  }
  #pragma unroll
  for(int jj = 0; jj < JT; jj++) atomicAdd(&racc_g[(j0+jj)*DN + tid], rAcc[jj]);
  #pragma unroll
  for(int ee = 0; ee < CHB; ee++) atomicAdd(&sEg[(e0+ee)*DN + tid], sE[ee]);
}

// ---- tail: hout = elu(h*sEg) everywhere; blocks 0..63 also do rout + alpha ----
// (reference's reshape(R,E,1)+softmax(axis=1) == per-row softmax on the e*64+j
//  flat array viewed as [64][4096]; b_lin dropped by shift invariance)
__global__ __launch_bounds__(256) void kTail(const float* __restrict__ h,
                                             const float* __restrict__ sEg,
                                             const float* __restrict__ alog,
                                             const float* __restrict__ r,
                                             const float* __restrict__ racc,
                                             float* __restrict__ hout,
                                             float* __restrict__ rout,
                                             float* __restrict__ aout){
  const int b = blockIdx.x, tid = threadIdx.x;
  {
    const int i = b*256 + tid;               // grid 4096 covers EN*DN
    float hp = h[i] * sEg[i];
    hout[i] = hp > 0.f ? hp : (ex2(hp*LOG2E) - 1.0f);
  }
  if(b < RN){                                 // block-uniform branch
    const int i = b*DN + tid;
    float v = r[i] * racc[i];
    rout[i] = v > 0.f ? v : (ex2(v*LOG2E) - 1.0f);

    const float* __restrict__ row = alog + b*EN;
    float exv[16]; float s = 0.f;
    #pragma unroll
    for(int k = 0; k < 16; k++){
      float v2 = ex2(row[k*256 + tid] * LOG2E);
      exv[k] = v2; s += v2;
    }
    #pragma unroll
    for(int off = 32; off > 0; off >>= 1) s += __shfl_xor(s, off, 64);
    __shared__ float wsum[4];
    if((tid & 63) == 0) wsum[tid>>6] = s;
    __syncthreads();
    float inv = 1.0f / (wsum[0] + wsum[1] + wsum[2] + wsum[3]);
    float* __restrict__ orow = aout + b*EN;
    #pragma unroll
    for(int k = 0; k < 16; k++) orow[k*256 + tid] = exv[k] * inv;
  }
}

extern "C" void kernel_launch(void* const* d_in, const int* in_sizes, int n_in,
                              void* d_out, int out_size, void* d_ws, size_t ws_size,
                              hipStream_t stream){
  (void)in_sizes; (void)n_in; (void)out_size; (void)ws_size;
  const float* h   = (const float*)d_in[0];
  const float* r   = (const float*)d_in[1];
  const float* adj = (const float*)d_in[2];
  const float* W   = (const float*)d_in[3];
  // d_in[4] = b_lin: unused (softmax shift invariance)

  float* ws   = (float*)d_ws;
  float* s2   = ws;                  // EN*RN   (written by kA, read by kB)
  float* lE   = s2 + EN*RN;          // RN*DN  --+ zeroed by memset
  float* lRg  = lE + RN*DN;          // EN*DN  --+
  float* racc = lRg + EN*DN;         // RN*DN  --+ zeroed by kA
  float* sEg  = racc + RN*DN;        // EN*DN  --+
  float* alog = sEg + EN*DN;         // EN*RN

  float* hout = (float*)d_out;           // EN*DN
  float* rout = hout + EN*DN;            // RN*DN
  float* aout = rout + RN*DN;            // RN*EN

  hipMemsetAsync(lE, 0, size_t(RN*DN + EN*DN)*sizeof(float), stream);
  kA   <<<GRIDAB,     256, 0, stream>>>(h, r, adj, s2, lRg, lE, (float4*)racc);
  kB   <<<GRIDAB,     256, 0, stream>>>(h, r, s2, lRg, lE, W, alog, racc, sEg);
  kTail<<<EN*DN/256,  256, 0, stream>>>(h, sEg, alog, r, racc, hout, rout, aout);
}

// Round 9
// 167.105 us; speedup vs baseline: 1.5828x; 1.5828x over previous
//
#include <hip/hip_runtime.h>

// RelatEntAtt: E=4096, R=64, D=256. Fully fused recompute; att (E,R,D) never
// materialized. exp2 with log2(e) folded into the adj-softmax output.
// R2 (180.9us): CH=8, JT=16, arrays SROA to regs. Grid 512 -> 18% occ.
// R3/R4 (FAILED): CH=4 breaks SROA (~470 MB scratch traffic). CH=8 + JT=16
//     private-array shapes are load-bearing. DO NOT TOUCH.
// R5 (181us): j-half split, grid 1024. kB 73->65us. SROA held.
// R6 (170us, PASSED, BEST): j-quarter split, grid 2048. kB 58.5us, VALUBusy
//     66%, FETCH 17.6MB. Within ~3% of the 4-dispatch structural floor
//     (kernel-sum ~125us + ~45us launch/boundary overhead).
// R7 (FAILED): hipLaunchCooperativeKernel incompatible with harness capture.
// R8 (FAILED): spin grid-barrier -> likely deadlock. NO SPINS.
// R9 (FAILED): last-arriver tails: agent acquire fence does NOT give in-kernel
//     plain-load visibility of remote-XCD atomics. Atomic results may only be
//     consumed across a kernel boundary.
// R10 (FAILED): bisection multi-reduce raised live regs +~30 -> spill (FETCH
//     182MB, VALU 11%). row16_sum's immediate-consume DPP scan is register-
//     minimal and load-bearing. Third confirmation of the register cliff.
// R11: R6 VERBATIM. All four structural levers (dispatch fusion, sync
//     restructure, inner-loop reduction rewrite, e/j-chunk resizing) are
//     empirically foreclosed on this chip/compiler/harness combination.

#define EN 4096
#define RN 64
#define DN 256
#define JT 16          // j-tile width (PROVEN SROA shape - do not change)
#define LOG2E 1.44269504088896340736f
#define CHA 8   // e's per block in kA (PROVEN SROA shape - do not change)
#define CHB 8   // e's per block in kB (PROVEN SROA shape - do not change)
#define ZERO_F4 ((RN*DN*2 + EN*DN*2)/4)   // float4 count of zeroed ws region

__device__ __forceinline__ float ex2(float x){ return __builtin_amdgcn_exp2f(x); }
__device__ __forceinline__ float rcpf(float x){ return __builtin_amdgcn_rcpf(x); }

template<int CTRL>
__device__ __forceinline__ float dpp_add(float v){
  int m = __builtin_amdgcn_update_dpp(0, __float_as_int(v), CTRL, 0xf, 0xf, true);
  return v + __int_as_float(m);
}
// lane (i%16)==15 ends with the sum of its 16-lane row
__device__ __forceinline__ float row16_sum(float v){
  v = dpp_add<0x111>(v);
  v = dpp_add<0x112>(v);
  v = dpp_add<0x114>(v);
  v = dpp_add<0x118>(v);
  return v;
}

// ---- s2[e,j] = softmax_j(adj[e,:]) * LOG2E;  also zeroes accumulator ws ----
__global__ __launch_bounds__(256) void k_adj(const float* __restrict__ adj,
                                             float* __restrict__ s2,
                                             float4* __restrict__ zbase){
  const int tid = threadIdx.x;
  const int gt  = blockIdx.x*256 + tid;          // grid 1024 -> 262144 threads
  for(int i = gt; i < ZERO_F4; i += (EN/4)*256)
    zbase[i] = make_float4(0.f, 0.f, 0.f, 0.f);
  const int lane = tid & 63;
  const int e = blockIdx.x*4 + (tid >> 6);
  float a = adj[e*RN + lane];
  float ev = ex2(a * LOG2E);
  float s = ev;
  #pragma unroll
  for(int off = 32; off > 0; off >>= 1) s += __shfl_xor(s, off, 64);
  s2[e*RN + lane] = ev * (LOG2E * rcpf(s));
}

// ---- kA: lRg[e,d] += sum_(own j) ev;  lE[j,d] += ev ----
// block = (e-chunk, j-quarter): e0 = (bid>>2)*CHA, j0 = (bid&3)*16
__global__ __launch_bounds__(256,4) void kA(const float* __restrict__ h,
                                            const float* __restrict__ r,
                                            const float* __restrict__ s2,
                                            float* __restrict__ lRg,
                                            float* __restrict__ lE){
  const int d  = threadIdx.x;
  const int e0 = (blockIdx.x >> 2) * CHA;
  const int j0 = (blockIdx.x & 3) * JT;
  __shared__ float s2s[CHA*JT];            // 512 B
  if(d < CHA*JT) s2s[d] = s2[(e0 + (d >> 4))*RN + j0 + (d & 15)];
  __syncthreads();

  float lR[CHA];
  #pragma unroll
  for(int ee = 0; ee < CHA; ee++) lR[ee] = 0.f;

  float rcol[JT], lEacc[JT];
  #pragma unroll
  for(int jj = 0; jj < JT; jj++){ rcol[jj] = r[(j0+jj)*DN + d]; lEacc[jj] = 0.f; }
  #pragma unroll
  for(int ee = 0; ee < CHA; ee++){
    const float he = h[(e0+ee)*DN + d];
    #pragma unroll
    for(int jj = 0; jj < JT; jj++){
      float t  = s2s[ee*JT + jj] * he * rcol[jj];
      float ev = ex2(fmaxf(t, 0.2f*t));
      lR[ee]   += ev;
      lEacc[jj] += ev;
    }
  }
  #pragma unroll
  for(int jj = 0; jj < JT; jj++) atomicAdd(&lE[(j0+jj)*DN + d], lEacc[jj]);
  #pragma unroll
  for(int ee = 0; ee < CHA; ee++) atomicAdd(&lRg[(e0+ee)*DN + d], lR[ee]);
}

// ---- kB: main fused sweep over own j-quarter ----
// per (e,d): pR = ev/lRg (att_R), pE = ev/lE (att_E)
//   sEg[e,d] += sum_(own j) pE      (atomics; h' ELU in kTail)
//   r'[j,d] += pR                   16-reg acc, atomic flush
//   alog[e,j] = sum_d pR*W_d        row16 DPP + LDS partial combine (j owned)
__global__ __launch_bounds__(256,4) void kB(const float* __restrict__ h,
                                            const float* __restrict__ r,
                                            const float* __restrict__ s2,
                                            const float* __restrict__ lRg,
                                            const float* __restrict__ lE,
                                            const float* __restrict__ W,
                                            float* __restrict__ alog,
                                            float* __restrict__ racc_g,
                                            float* __restrict__ sEg){
  const int tid  = threadIdx.x;            // = d
  const int lane = tid & 63;
  const int grp  = tid >> 4;               // 16 groups of 16 lanes
  const int e0   = (blockIdx.x >> 2) * CHB;
  const int j0   = (blockIdx.x & 3) * JT;
  __shared__ float s2s[CHB*JT];            // 512 B
  __shared__ float apart[CHB*16*20];       // [ee][g][jj], jj stride 1, g stride 20 -> 10 KB
  if(tid < CHB*JT) s2s[tid] = s2[(e0 + (tid >> 4))*RN + j0 + (tid & 15)];
  __syncthreads();

  const float wd = W[tid];
  float sE[CHB];
  #pragma unroll
  for(int ee = 0; ee < CHB; ee++) sE[ee] = 0.f;

  float rcol[JT], ile[JT], rAcc[JT];
  #pragma unroll
  for(int jj = 0; jj < JT; jj++){
    const int j = j0 + jj;
    rcol[jj] = r[j*DN + tid];
    ile[jj]  = rcpf(lE[j*DN + tid]);
    rAcc[jj] = 0.f;
  }
  for(int ee = 0; ee < CHB; ee++){
    const int e = e0 + ee;
    const float he = h[e*DN + tid];
    const float il = rcpf(lRg[e*DN + tid]);
    const float u  = il * wd;
    #pragma unroll
    for(int jg = 0; jg < JT/4; jg++){
      float4 st;
      #pragma unroll
      for(int jj4 = 0; jj4 < 4; jj4++){
        const int jj = jg*4 + jj4;
        float t  = s2s[ee*JT + jj] * he * rcol[jj];
        float ev = ex2(fmaxf(t, 0.2f*t));
        rAcc[jj] = fmaf(ev, il, rAcc[jj]);      // pR accumulated over e
        sE[ee]   = fmaf(ev, ile[jj], sE[ee]);   // pE sum over own j
        float rs = row16_sum(ev * u);           // alog contribution
        if(jj4==0) st.x = rs; else if(jj4==1) st.y = rs;
        else if(jj4==2) st.z = rs; else st.w = rs;
      }
      if((lane & 15) == 15){
        *reinterpret_cast<float4*>(&apart[(ee*16 + grp)*20 + jg*4]) = st;
      }
    }
  }
  __syncthreads();
  if(tid < CHB*JT){                        // 128 threads: ee = tid>>4, jj = tid&15
    const int ee = tid >> 4, jj = tid & 15;
    float sum = 0.f;
    #pragma unroll
    for(int g = 0; g < 16; g++) sum += apart[(ee*16 + g)*20 + jj];
    alog[(e0+ee)*RN + j0 + jj] = sum;
  }
  #pragma unroll
  for(int jj = 0; jj < JT; jj++) atomicAdd(&racc_g[(j0+jj)*DN + tid], rAcc[jj]);
  #pragma unroll
  for(int ee = 0; ee < CHB; ee++) atomicAdd(&sEg[(e0+ee)*DN + tid], sE[ee]);
}

// ---- tail: hout = elu(h*sEg) everywhere; blocks 0..63 also do rout + alpha ----
// (reference's reshape(R,E,1)+softmax(axis=1) == per-row softmax on the e*64+j
//  flat array viewed as [64][4096]; b_lin dropped by shift invariance)
__global__ __launch_bounds__(256) void kTail(const float* __restrict__ h,
                                             const float* __restrict__ sEg,
                                             const float* __restrict__ alog,
                                             const float* __restrict__ r,
                                             const float* __restrict__ racc,
                                             float* __restrict__ hout,
                                             float* __restrict__ rout,
                                             float* __restrict__ aout){
  const int b = blockIdx.x, tid = threadIdx.x;
  {
    const int i = b*256 + tid;               // grid 4096 covers EN*DN
    float hp = h[i] * sEg[i];
    hout[i] = hp > 0.f ? hp : (ex2(hp*LOG2E) - 1.0f);
  }
  if(b < RN){                                 // block-uniform branch
    const int i = b*DN + tid;
    float v = r[i] * racc[i];
    rout[i] = v > 0.f ? v : (ex2(v*LOG2E) - 1.0f);

    const float* __restrict__ row = alog + b*EN;
    float exv[16]; float s = 0.f;
    #pragma unroll
    for(int k = 0; k < 16; k++){
      float v2 = ex2(row[k*256 + tid] * LOG2E);
      exv[k] = v2; s += v2;
    }
    #pragma unroll
    for(int off = 32; off > 0; off >>= 1) s += __shfl_xor(s, off, 64);
    __shared__ float wsum[4];
    if((tid & 63) == 0) wsum[tid>>6] = s;
    __syncthreads();
    float inv = 1.0f / (wsum[0] + wsum[1] + wsum[2] + wsum[3]);
    float* __restrict__ orow = aout + b*EN;
    #pragma unroll
    for(int k = 0; k < 16; k++) orow[k*256 + tid] = exv[k] * inv;
  }
}

extern "C" void kernel_launch(void* const* d_in, const int* in_sizes, int n_in,
                              void* d_out, int out_size, void* d_ws, size_t ws_size,
                              hipStream_t stream){
  (void)in_sizes; (void)n_in; (void)out_size; (void)ws_size;
  const float* h   = (const float*)d_in[0];
  const float* r   = (const float*)d_in[1];
  const float* adj = (const float*)d_in[2];
  const float* W   = (const float*)d_in[3];
  // d_in[4] = b_lin: unused (softmax shift invariance)

  float* ws   = (float*)d_ws;
  float* s2   = ws;                  // EN*RN
  float* lE   = s2 + EN*RN;          // RN*DN  --+
  float* racc = lE + RN*DN;          // RN*DN    | zeroed by k_adj
  float* lRg  = racc + RN*DN;        // EN*DN    |
  float* sEg  = lRg + EN*DN;         // EN*DN  --+
  float* alog = sEg + EN*DN;         // EN*RN

  float* hout = (float*)d_out;           // EN*DN
  float* rout = hout + EN*DN;            // RN*DN
  float* aout = rout + RN*DN;            // RN*EN

  k_adj<<<EN/4,      256, 0, stream>>>(adj, s2, (float4*)lE);
  kA   <<<EN/CHA*4,  256, 0, stream>>>(h, r, s2, lRg, lE);
  kB   <<<EN/CHB*4,  256, 0, stream>>>(h, r, s2, lRg, lE, W, alog, racc, sEg);
  kTail<<<EN*DN/256, 256, 0, stream>>>(h, sEg, alog, r, racc, hout, rout, aout);
}